// Round 15
// baseline (2559.081 us; speedup 1.0000x reference)
//
#include <hip/hip_runtime.h>

// Problem constants
#define BB 2048   // batch
#define TT 128    // timesteps
#define VV 25     // input features
#define HH 512    // hidden
#define NC 100    // classes

typedef __attribute__((ext_vector_type(8))) _Float16 half8;
typedef __attribute__((ext_vector_type(4))) float f32x4;

__device__ __forceinline__ float fsigmoid(float x) { return 1.0f / (1.0f + __expf(-x)); }
__device__ __forceinline__ float ftanh(float x) {
    float e = __expf(2.0f * x);
    return 1.0f - 2.0f / (e + 1.0f);
}

// ---- prep: weights -> MFMA-fragment-native fp16 layout ----
// WT[kq][n] : 16B group = fp16(W[n][kq*8 .. kq*8+7])  (kq 0..63 = W_hh,
// 64..67 = W_ih zero-padded to K=32). B-frag load for K32 chunk cc:
// lane(col,quad) reads WT[cc*4+quad][n0+col] -> 4 x 256B segments.
__global__ __launch_bounds__(256) void prep_whh_t(const float* __restrict__ W,
                                                  _Float16* __restrict__ WT) {
    int i = blockIdx.x * 256 + threadIdx.x;   // 2048 n x 64 kq, grid 512
    int n = i & 2047, kq = i >> 11;
    half8 h8;
    #pragma unroll
    for (int j = 0; j < 8; ++j) h8[j] = (_Float16)W[(size_t)n * HH + kq * 8 + j];  // RNE cvt
    ((half8*)WT)[(size_t)kq * 2048 + n] = h8;
}

__global__ __launch_bounds__(256) void prep_wih_t(const float* __restrict__ W,
                                                  _Float16* __restrict__ WT) {
    int i = blockIdx.x * 256 + threadIdx.x;   // 2048 n x 4 kq, grid 32
    int n = i & 2047, kq4 = i >> 11;
    half8 h8;
    #pragma unroll
    for (int j = 0; j < 8; ++j) {
        int k = kq4 * 8 + j;
        h8[j] = (k < VV) ? (_Float16)W[(size_t)n * VV + k] : (_Float16)0.0f;
    }
    ((half8*)WT)[(size_t)(64 + kq4) * 2048 + n] = h8;
}

// One LSTM timestep — ZERO LDS, ZERO barriers. r13's shape (256 thr = 4
// waves, 64 batch x 32 j x 4 gates, 2 blocks/CU, 2 waves/SIMD) but both A
// (h, gathered frag-direct: per row 64 contiguous B, L1 completes the 128B
// lines across chunk pairs) and B (frag-native WT) stream register-direct
// from L2 via a 4-slot rolling pipeline (~3 chunks of latency cover; r7's
// failure was 1-chunk cover + an XCD-scattering swizzle). No __syncthreads
// -> compiler emits only fine-grained vmcnt, no vmcnt(0) drains.
// Natural x-major grid: bid%8 = bx%8 -> the 16 by-blocks of one bx share an
// XCD, so h written at step t-1 is read from the SAME XCD's L2 at step t.
// Launch-per-step = the cheap global barrier (r9/r11).
__global__ __launch_bounds__(256, 2) void lstm_step(
    const float* __restrict__ msg, int t,
    const _Float16* __restrict__ WT,
    const float* __restrict__ b_ih, const float* __restrict__ b_hh,
    const _Float16* __restrict__ hin, _Float16* __restrict__ hout,
    float* __restrict__ c)
{
    const int b0 = blockIdx.x * 64;
    const int j0 = blockIdx.y * 32;
    const int tid = threadIdx.x;
    const int lane = tid & 63;
    const int w = tid >> 6;
    const int wm = w & 1, wn = w >> 1;
    const int col = lane & 15, quad = lane >> 4;
    const int jj = j0 + wn * 16 + col;

    f32x4 acc[2][4];   // [tm][gate]
    #pragma unroll
    for (int g = 0; g < 4; ++g) {
        float bias = b_ih[g * HH + jj] + b_hh[g * HH + jj];
        f32x4 bv = {bias, bias, bias, bias};
        acc[0][g] = bv;
        acc[1][g] = bv;
    }

    // A frag-direct gather pointers: lane(col,quad) reads 8 k at quad*8
    const _Float16* arow[2];
    #pragma unroll
    for (int tm = 0; tm < 2; ++tm)
        arow[tm] = hin + (size_t)(b0 + wm * 32 + tm * 16 + col) * HH + quad * 8;

    const half8* WT8 = (const half8*)WT;
    int bidx[4];
    #pragma unroll
    for (int g = 0; g < 4; ++g) bidx[g] = quad * 2048 + g * HH + j0 + wn * 16 + col;

    // 4-slot rolling pipeline (As 32 + Bs 64 VGPR)
    half8 As[4][2], Bs[4][4];
    #pragma unroll
    for (int p = 0; p < 4; ++p) {            // prologue: chunks 0..3
        #pragma unroll
        for (int tm = 0; tm < 2; ++tm) As[p][tm] = *(const half8*)(arow[tm] + p * 32);
        #pragma unroll
        for (int g = 0; g < 4; ++g) Bs[p][g] = WT8[p * 8192 + bidx[g]];
    }

    #pragma unroll
    for (int cc = 0; cc < 17; ++cc) {        // 16 K32 chunks of W_hh + x-tail
        const int s = cc & 3;
        #pragma unroll
        for (int tm = 0; tm < 2; ++tm)
            #pragma unroll
            for (int g = 0; g < 4; ++g)
                acc[tm][g] = __builtin_amdgcn_mfma_f32_16x16x32_f16(As[s][tm], Bs[s][g], acc[tm][g], 0, 0, 0);
        const int nc = cc + 4;
        if (nc <= 15) {
            #pragma unroll
            for (int tm = 0; tm < 2; ++tm) As[s][tm] = *(const half8*)(arow[tm] + nc * 32);
            #pragma unroll
            for (int g = 0; g < 4; ++g) Bs[s][g] = WT8[nc * 8192 + bidx[g]];
        } else if (nc == 16) {
            // x-tail: msg (K=25 zero-padded to 32), fp16 convert in regs
            #pragma unroll
            for (int tm = 0; tm < 2; ++tm) {
                const float* mrow = msg + ((size_t)(b0 + wm * 32 + tm * 16 + col) * TT + t) * VV;
                half8 xh;
                #pragma unroll
                for (int i = 0; i < 8; ++i) {
                    int k = quad * 8 + i;
                    xh[i] = (k < VV) ? (_Float16)mrow[k] : (_Float16)0.0f;
                }
                As[s][tm] = xh;
            }
            #pragma unroll
            for (int g = 0; g < 4; ++g) Bs[s][g] = WT8[16 * 8192 + bidx[g]];
        }
    }

    // ---- cell update; h written as a single fp16 plane ----
    // C/D layout: col=lane&15 (=n), row=quad*4+reg  [m89]
    #pragma unroll
    for (int tm = 0; tm < 2; ++tm) {
        #pragma unroll
        for (int reg = 0; reg < 4; ++reg) {
            int b = b0 + wm * 32 + tm * 16 + quad * 4 + reg;
            size_t idx = (size_t)b * HH + jj;
            float i_ = fsigmoid(acc[tm][0][reg]);
            float f_ = fsigmoid(acc[tm][1][reg]);
            float g_ = ftanh(acc[tm][2][reg]);
            float o_ = fsigmoid(acc[tm][3][reg]);
            float cn = f_ * c[idx] + i_ * g_;
            c[idx] = cn;
            hout[idx] = (_Float16)(o_ * ftanh(cn));
        }
    }
}

// out[b, cls] = dot(h, W_fc[cls]) + b_fc[cls]. 4 rows/block.
__global__ __launch_bounds__(256) void fc_kernel(
    const _Float16* __restrict__ h, const float* __restrict__ W_fc,
    const float* __restrict__ b_fc, float* __restrict__ out)
{
    __shared__ float hs[4][HH];
    const int b0 = blockIdx.x * 4;
    for (int i = threadIdx.x; i < 4 * HH; i += 256) {
        int r = i >> 9, k = i & 511;
        hs[r][k] = (float)h[(size_t)(b0 + r) * HH + k];
    }
    __syncthreads();
    const int tid = threadIdx.x;
    if (tid < 2 * NC) {
        int r = tid / NC, cls = tid % NC;
        const float4* wv = (const float4*)(W_fc + (size_t)cls * HH);
        const float4* h0 = (const float4*)hs[r];
        const float4* h1 = (const float4*)hs[r + 2];
        float s0 = 0.0f, s1 = 0.0f;
        #pragma unroll 4
        for (int k = 0; k < HH / 4; ++k) {
            float4 ww = wv[k];
            float4 a0 = h0[k], a1 = h1[k];
            s0 += a0.x * ww.x + a0.y * ww.y + a0.z * ww.z + a0.w * ww.w;
            s1 += a1.x * ww.x + a1.y * ww.y + a1.z * ww.z + a1.w * ww.w;
        }
        out[(size_t)(b0 + r) * NC + cls] = s0 + b_fc[cls];
        out[(size_t)(b0 + r + 2) * NC + cls] = s1 + b_fc[cls];
    }
}

extern "C" void kernel_launch(void* const* d_in, const int* in_sizes, int n_in,
                              void* d_out, int out_size, void* d_ws, size_t ws_size,
                              hipStream_t stream) {
    const float* msg  = (const float*)d_in[0];
    const float* W_ih = (const float*)d_in[1];
    const float* W_hh = (const float*)d_in[2];
    const float* b_ih = (const float*)d_in[3];
    const float* b_hh = (const float*)d_in[4];
    const float* W_fc = (const float*)d_in[5];
    const float* b_fc = (const float*)d_in[6];
    float* out = (float*)d_out;

    // ws: c(4MB) | h0 h1 (fp16, 2MB ea) | WT (fp16, 2.23MB) = 10.2MB
    float*    c  = (float*)d_ws;
    _Float16* h0 = (_Float16*)(c + (size_t)BB * HH);
    _Float16* h1 = h0 + (size_t)BB * HH;
    _Float16* WT = h1 + (size_t)BB * HH;

    // zero c + h0 (contiguous 6 MB); h1 fully written at t=0
    hipMemsetAsync(d_ws, 0, (size_t)BB * HH * 4 + (size_t)BB * HH * 2, stream);

    prep_whh_t<<<512, 256, 0, stream>>>(W_hh, WT);
    prep_wih_t<<<32, 256, 0, stream>>>(W_ih, WT);

    _Float16 *hin = h0, *hout = h1;
    for (int t = 0; t < TT; ++t) {
        lstm_step<<<dim3(BB / 64, HH / 32), 256, 0, stream>>>(
            msg, t, WT, b_ih, b_hh, hin, hout, c);
        _Float16* tmp = hin; hin = hout; hout = tmp;
    }
    fc_kernel<<<BB / 4, 256, 0, stream>>>(hin, W_fc, b_fc, out);
}

// Round 16
// 1574.168 us; speedup vs baseline: 1.6257x; 1.6257x over previous
//
#include <hip/hip_runtime.h>

// Problem constants
#define BB 2048   // batch
#define TT 128    // timesteps
#define VV 25     // input features
#define HH 512    // hidden
#define NC 100    // classes

typedef __attribute__((ext_vector_type(8))) _Float16 half8;
typedef __attribute__((ext_vector_type(4))) float f32x4;

__device__ __forceinline__ float fsigmoid(float x) { return 1.0f / (1.0f + __expf(-x)); }
__device__ __forceinline__ float ftanh(float x) {
    float e = __expf(2.0f * x);
    return 1.0f - 2.0f / (e + 1.0f);
}

// ---- prep: weights -> MFMA-fragment-native fp16 layout ----
// WT[kq][n] : 16B group = fp16(W[n][kq*8 .. kq*8+7])  (kq 0..63 = W_hh,
// 64..67 = W_ih zero-padded to K=32). B-frag load for K32 chunk cc:
// lane(col,quad) reads WT[cc*4+quad][n0+col] -> 4 x 256B segments.
__global__ __launch_bounds__(256) void prep_whh_t(const float* __restrict__ W,
                                                  _Float16* __restrict__ WT) {
    int i = blockIdx.x * 256 + threadIdx.x;   // 2048 n x 64 kq, grid 512
    int n = i & 2047, kq = i >> 11;
    half8 h8;
    #pragma unroll
    for (int j = 0; j < 8; ++j) h8[j] = (_Float16)W[(size_t)n * HH + kq * 8 + j];  // RNE cvt
    ((half8*)WT)[(size_t)kq * 2048 + n] = h8;
}

__global__ __launch_bounds__(256) void prep_wih_t(const float* __restrict__ W,
                                                  _Float16* __restrict__ WT) {
    int i = blockIdx.x * 256 + threadIdx.x;   // 2048 n x 4 kq, grid 32
    int n = i & 2047, kq4 = i >> 11;
    half8 h8;
    #pragma unroll
    for (int j = 0; j < 8; ++j) {
        int k = kq4 * 8 + j;
        h8[j] = (k < VV) ? (_Float16)W[(size_t)n * VV + k] : (_Float16)0.0f;
    }
    ((half8*)WT)[(size_t)(64 + kq4) * 2048 + n] = h8;
}

// One LSTM timestep — r13's structure with the ENTIRE A tile staged up
// front: exactly ONE __syncthreads per step (r13 had 9; each drained the
// B-prefetch queue via the compiler's vmcnt(0)-before-barrier).
// Full A tile = 64 rows x 544 k fp16 (512 W_hh + 32 x-tail) = 70.7 KB with
// padding; 2 blocks/CU uses 141 KB of the 160 KB LDS.
// Block = 256 thr (4 waves) = 64 batch x 32 j (x4 gates); wave w: wm=w&1
// (32-batch half), wn=w>>1 (16-j half); wave tile 2 m x 4 gates, 16x16x32
// f16 MFMA. B-frags stream register-direct from L2 (frag-native WT) through
// a 4-slot rolling prefetch that is never drained (only fine-grained vmcnt).
// Row stride 552 halves (1104 B == 80 mod 128): frag ds_read_b128 phases
// spread over all 8 bank windows (2-way, free); staging writes reuse r13's
// proven conflict-free pattern per 64-k chunk.
// Launch-per-step = the cheap global barrier (r9/r11: anything in-kernel
// cross-XCD is far worse).
__global__ __launch_bounds__(256, 2) void lstm_step(
    const float* __restrict__ msg, int t,
    const _Float16* __restrict__ WT,
    const float* __restrict__ b_ih, const float* __restrict__ b_hh,
    const _Float16* __restrict__ hin, _Float16* __restrict__ hout,
    float* __restrict__ c)
{
    const int b0 = blockIdx.x * 64;
    const int j0 = blockIdx.y * 32;
    const int tid = threadIdx.x;
    const int lane = tid & 63;
    const int w = tid >> 6;
    const int wm = w & 1, wn = w >> 1;
    const int col = lane & 15, quad = lane >> 4;
    const int jj = j0 + wn * 16 + col;

    // [row][k]: 64 x 552 halves (544 data + 8 pad) = 70,656 B
    __shared__ _Float16 Abuf[64][552];

    f32x4 acc[2][4];   // [tm][gate]
    #pragma unroll
    for (int g = 0; g < 4; ++g) {
        float bias = b_ih[g * HH + jj] + b_hh[g * HH + jj];
        f32x4 bv = {bias, bias, bias, bias};
        acc[0][g] = bv;
        acc[1][g] = bv;
    }

    const half8* WT8 = (const half8*)WT;
    int bidx[4];
    #pragma unroll
    for (int g = 0; g < 4; ++g) bidx[g] = quad * 2048 + g * HH + j0 + wn * 16 + col;

    half8 Bs[4][4];   // rolling B slots (chunk & 3)
    #pragma unroll
    for (int p = 0; p < 4; ++p)
        #pragma unroll
        for (int g = 0; g < 4; ++g) Bs[p][g] = WT8[p * 8192 + bidx[g]];

    // ---- stage the FULL A tile (r13's conflict-free pattern, x8 chunks) ----
    // thread -> (row = tid>>2, 16-half seg = (tid&3)*16) within each 64-k chunk
    const int arow = tid >> 2, aseg = (tid & 3) << 4;
    const _Float16* aph = hin + (size_t)(b0 + arow) * HH + aseg;
    #pragma unroll
    for (int cch = 0; cch < 8; ++cch) {
        half8 r0 = *(const half8*)(aph + cch * 64);
        half8 r1 = *(const half8*)(aph + cch * 64 + 8);
        *(half8*)&Abuf[arow][cch * 64 + aseg]     = r0;
        *(half8*)&Abuf[arow][cch * 64 + aseg + 8] = r1;
    }
    {   // x-tail: msg (K=25 zero-padded to 32) -> columns 512..544
        const int xseg = (tid & 3) << 3;
        const size_t mb = ((size_t)(b0 + arow) * TT + t) * VV;
        half8 xh;
        #pragma unroll
        for (int i = 0; i < 8; ++i) {
            int k = xseg + i;
            xh[i] = (k < VV) ? (_Float16)msg[mb + k] : (_Float16)0.0f;
        }
        *(half8*)&Abuf[arow][512 + xseg] = xh;
    }
    __syncthreads();   // the ONLY barrier

    // ---- 17 K32 chunks, barrier-free; B prefetch rolls 4 ahead ----
    #pragma unroll
    for (int cc = 0; cc < 17; ++cc) {
        const int s = cc & 3;
        half8 ahf[2];
        #pragma unroll
        for (int tm = 0; tm < 2; ++tm)
            ahf[tm] = *(const half8*)&Abuf[wm * 32 + tm * 16 + col][cc * 32 + quad * 8];
        #pragma unroll
        for (int tm = 0; tm < 2; ++tm)
            #pragma unroll
            for (int g = 0; g < 4; ++g)
                acc[tm][g] = __builtin_amdgcn_mfma_f32_16x16x32_f16(ahf[tm], Bs[s][g], acc[tm][g], 0, 0, 0);
        const int nc = cc + 4;
        if (nc <= 16) {
            #pragma unroll
            for (int g = 0; g < 4; ++g) Bs[s][g] = WT8[nc * 8192 + bidx[g]];
        }
    }

    // ---- cell update; h written as a single fp16 plane ----
    // C/D layout: col=lane&15 (=n), row=quad*4+reg  [m89]
    #pragma unroll
    for (int tm = 0; tm < 2; ++tm) {
        #pragma unroll
        for (int reg = 0; reg < 4; ++reg) {
            int b = b0 + wm * 32 + tm * 16 + quad * 4 + reg;
            size_t idx = (size_t)b * HH + jj;
            float i_ = fsigmoid(acc[tm][0][reg]);
            float f_ = fsigmoid(acc[tm][1][reg]);
            float g_ = ftanh(acc[tm][2][reg]);
            float o_ = fsigmoid(acc[tm][3][reg]);
            float cn = f_ * c[idx] + i_ * g_;
            c[idx] = cn;
            hout[idx] = (_Float16)(o_ * ftanh(cn));
        }
    }
}

// out[b, cls] = dot(h, W_fc[cls]) + b_fc[cls]. 4 rows/block.
__global__ __launch_bounds__(256) void fc_kernel(
    const _Float16* __restrict__ h, const float* __restrict__ W_fc,
    const float* __restrict__ b_fc, float* __restrict__ out)
{
    __shared__ float hs[4][HH];
    const int b0 = blockIdx.x * 4;
    for (int i = threadIdx.x; i < 4 * HH; i += 256) {
        int r = i >> 9, k = i & 511;
        hs[r][k] = (float)h[(size_t)(b0 + r) * HH + k];
    }
    __syncthreads();
    const int tid = threadIdx.x;
    if (tid < 2 * NC) {
        int r = tid / NC, cls = tid % NC;
        const float4* wv = (const float4*)(W_fc + (size_t)cls * HH);
        const float4* h0 = (const float4*)hs[r];
        const float4* h1 = (const float4*)hs[r + 2];
        float s0 = 0.0f, s1 = 0.0f;
        #pragma unroll 4
        for (int k = 0; k < HH / 4; ++k) {
            float4 ww = wv[k];
            float4 a0 = h0[k], a1 = h1[k];
            s0 += a0.x * ww.x + a0.y * ww.y + a0.z * ww.z + a0.w * ww.w;
            s1 += a1.x * ww.x + a1.y * ww.y + a1.z * ww.z + a1.w * ww.w;
        }
        out[(size_t)(b0 + r) * NC + cls] = s0 + b_fc[cls];
        out[(size_t)(b0 + r + 2) * NC + cls] = s1 + b_fc[cls];
    }
}

extern "C" void kernel_launch(void* const* d_in, const int* in_sizes, int n_in,
                              void* d_out, int out_size, void* d_ws, size_t ws_size,
                              hipStream_t stream) {
    const float* msg  = (const float*)d_in[0];
    const float* W_ih = (const float*)d_in[1];
    const float* W_hh = (const float*)d_in[2];
    const float* b_ih = (const float*)d_in[3];
    const float* b_hh = (const float*)d_in[4];
    const float* W_fc = (const float*)d_in[5];
    const float* b_fc = (const float*)d_in[6];
    float* out = (float*)d_out;

    // ws: c(4MB) | h0 h1 (fp16, 2MB ea) | WT (fp16, 2.23MB) = 10.2MB
    float*    c  = (float*)d_ws;
    _Float16* h0 = (_Float16*)(c + (size_t)BB * HH);
    _Float16* h1 = h0 + (size_t)BB * HH;
    _Float16* WT = h1 + (size_t)BB * HH;

    // zero c + h0 (contiguous 6 MB); h1 fully written at t=0
    hipMemsetAsync(d_ws, 0, (size_t)BB * HH * 4 + (size_t)BB * HH * 2, stream);

    prep_whh_t<<<512, 256, 0, stream>>>(W_hh, WT);
    prep_wih_t<<<32, 256, 0, stream>>>(W_ih, WT);

    _Float16 *hin = h0, *hout = h1;
    for (int t = 0; t < TT; ++t) {
        lstm_step<<<dim3(BB / 64, HH / 32), 256, 0, stream>>>(
            msg, t, WT, b_ih, b_hh, hin, hout, c);
        _Float16* tmp = hin; hin = hout; hout = tmp;
    }
    fc_kernel<<<BB / 4, 256, 0, stream>>>(hin, W_fc, b_fc, out);
}